// Round 5
// baseline (149.620 us; speedup 1.0000x reference)
//
#include <hip/hip_runtime.h>
#include <hip/hip_fp16.h>

#define NSITES 262144

struct alignas(16) H8 { __half2 h[4]; };   // 8 fp16 values = 16 B
typedef __attribute__((ext_vector_type(2))) float floatx2;
typedef __attribute__((ext_vector_type(4))) unsigned int uintx4;

// Round-4 post-mortem: volatile-asm forced a genuine 12-wide gather batch
// (VGPR 28 = 24 asm outputs + 4 spw, all live) and NOTHING changed — 5
// different schedules all sit at 47-48us. The kernel is throughput-bound on
// the random-line-fill path: G8 (8 MiB) vs 4 MiB per-XCD L2 + uniform-random
// indices -> every XCD works against the full 8 MiB -> 47% miss, ~95 MB of
// 64B fills at ~2 TB/s = the wall. fp4/fp6 compression is closed: g ~ N(0,64)
// (Weff sums 8 normals), fp8 tails already produce the absmax 5.5 of 12.24.
//
// Fix: SPLIT BY BATCH-PAIR. Ga = batches {0,1} (4 MiB), Gb = {2,3} (4 MiB),
// Sp split likewise. Two gather passes, each with a 4 MiB random footprint
// that fits ENTIRELY in each XCD's L2 -> capacity misses vanish after cold
// fill. Cost: NN read twice (+12 MB), one extra launch. Math unchanged.
//
// ws layout:
//   Ga [NSITES][2] uint2  fp8, 16 B/site   (4 MiB)   batches 0,1
//   Gb [NSITES][2] uint2  fp8, 16 B/site   (4 MiB)   batches 2,3
//   Spa[NSITES][2] H8    fp16, 32 B/site   (8 MiB)   batches 0,1
//   Spb[NSITES][2] H8    fp16, 32 B/site   (8 MiB)   batches 2,3

__global__ __launch_bounds__(256) void prep_kernel(
    const float* __restrict__ In,       // [4][8][NSITES]
    const float* __restrict__ Weights,  // [8][8][16]
    const float* __restrict__ bias,     // [8][8]
    uint2* __restrict__ Ga, uint2* __restrict__ Gb,
    H8*    __restrict__ Spa, H8* __restrict__ Spb)
{
    __shared__ float ws[8][8], wn[8][8], be[8];
    int t = threadIdx.x;
    if (t < 64) {
        int o = t >> 3, k = t & 7;
        float s0 = 0.f, s1 = 0.f;
        #pragma unroll
        for (int s = 0; s < 8; ++s) {
            s0 += Weights[s*128 + o*16 + k];
            s1 += Weights[s*128 + o*16 + 8 + k];
        }
        ws[o][k] = s0; wn[o][k] = s1;
    } else if (t < 72) {
        int o = t - 64;
        float s = 0.f;
        #pragma unroll
        for (int q = 0; q < 8; ++q) s += bias[q*8 + o];
        be[o] = s;
    }
    __syncthreads();

    int b    = t & 3;                    // batch
    int sl   = t >> 2;                   // 0..63
    int site = blockIdx.x * 64 + sl;

    float x[8];
    #pragma unroll
    for (int i = 0; i < 8; ++i)
        x[i] = In[(b*8 + i) * NSITES + site];   // 4×64B segments per wave-load

    float g[8], s[8];
    #pragma unroll
    for (int o = 0; o < 8; ++o) {
        float a0 = 0.f, a1 = be[o];
        #pragma unroll
        for (int i = 0; i < 8; ++i) {
            a0 = fmaf(wn[o][i], x[i], a0);
            a1 = fmaf(ws[o][i], x[i], a1);
        }
        g[o] = a0; s[o] = a1;
    }

    unsigned int w0 = 0, w1 = 0;
    w0 = __builtin_amdgcn_cvt_pk_fp8_f32(g[0], g[1], w0, false);
    w0 = __builtin_amdgcn_cvt_pk_fp8_f32(g[2], g[3], w0, true);
    w1 = __builtin_amdgcn_cvt_pk_fp8_f32(g[4], g[5], w1, false);
    w1 = __builtin_amdgcn_cvt_pk_fp8_f32(g[6], g[7], w1, true);

    // batch pair selects the array; (b&1) selects the half-record
    uint2* gd = (b < 2) ? Ga : Gb;
    gd[site*2 + (b & 1)] = make_uint2(w0, w1);   // wave: 2×256B segments

    H8 sv;
    #pragma unroll
    for (int p = 0; p < 4; ++p) sv.h[p] = __floats2half2_rn(s[2*p], s[2*p+1]);
    H8* sd = (b < 2) ? Spa : Spb;
    sd[site*2 + (b & 1)] = sv;                   // wave: 2×512B segments
}

// One pass over one batch-pair: 2 lanes per site (q2 = half-record), 128
// sites per block. Gather = 8 B/lane, 2 lanes share a 16 B record; random
// footprint = 4 MiB = one XCD L2. Streams (NN, Sp, out) stay nontemporal so
// they don't evict the L2-resident G partition.
__global__ __launch_bounds__(256) void gather_kernel(
    const H8*    __restrict__ Sp2,   // [NSITES][2] for this pass
    const uint2* __restrict__ G2,    // [NSITES][2] for this pass
    const int*   __restrict__ NN,    // [13][NSITES], rows 1..12 used
    float*       __restrict__ out,   // [32][NSITES]
    int bofs)                        // 0 or 2
{
    int t    = threadIdx.x;        // 256
    int q2   = t & 1;              // half-record index within the pair
    int sl   = t >> 1;             // local site 0..127
    int base = blockIdx.x * 128;
    int n    = base + sl;

    int m[12];
    #pragma unroll
    for (int z = 0; z < 12; ++z)
        m[z] = __builtin_nontemporal_load(&NN[(z + 1) * NSITES + n]);

    uintx4 spw = __builtin_nontemporal_load((const uintx4*)Sp2 + (n*2 + q2));
    float sp[8];
    #pragma unroll
    for (int p = 0; p < 4; ++p) {
        unsigned int wd = spw[p];
        __half2 h; __builtin_memcpy(&h, &wd, 4);
        float2 f = __half22float2(h);
        sp[2*p] = f.x; sp[2*p+1] = f.y;
    }

    const float NLOG2E = -1.44269504f;
    float acc[8], prod[8];
    #pragma unroll
    for (int k = 0; k < 8; ++k) { acc[k] = 0.f; prod[k] = 1.f; }

    #pragma unroll
    for (int z = 0; z < 12; ++z) {
        uint2 gw = G2[m[z]*2 + q2];          // cached: L2-resident partition
        float g[8];
        floatx2 p;
        p = __builtin_amdgcn_cvt_pk_f32_fp8(gw.x, false); g[0]=p[0]; g[1]=p[1];
        p = __builtin_amdgcn_cvt_pk_f32_fp8(gw.x, true ); g[2]=p[0]; g[3]=p[1];
        p = __builtin_amdgcn_cvt_pk_f32_fp8(gw.y, false); g[4]=p[0]; g[5]=p[1];
        p = __builtin_amdgcn_cvt_pk_f32_fp8(gw.y, true ); g[6]=p[0]; g[7]=p[1];
        #pragma unroll
        for (int k = 0; k < 8; ++k) {
            float x  = sp[k] + g[k];
            float ax = fabsf(x);
            acc[k] += fmaxf(x, 0.f);
            float e = __builtin_amdgcn_exp2f(ax * NLOG2E);  // e^-|x|
            prod[k] = fmaf(prod[k], e, prod[k]);            // Π (1+e^-|x|)  (≤ 2^12)
        }
    }

    // stores: per k-instruction, even/odd lanes hit rows j and j+8 over 32
    // consecutive sites -> 2×128B aligned segments.
    int j8 = (bofs + q2) * 8;
    #pragma unroll
    for (int k = 0; k < 8; ++k) {
        float r = acc[k] + 0.69314718f * __builtin_amdgcn_logf(prod[k]);
        __builtin_nontemporal_store(r, &out[(j8 + k) * NSITES + n]);
    }
}

extern "C" void kernel_launch(void* const* d_in, const int* in_sizes, int n_in,
                              void* d_out, int out_size, void* d_ws, size_t ws_size,
                              hipStream_t stream) {
    const float* In      = (const float*)d_in[0];
    const int*   NN      = (const int*)  d_in[1];
    const float* Weights = (const float*)d_in[2];
    const float* bias    = (const float*)d_in[3];
    float* out = (float*)d_out;

    char* w = (char*)d_ws;
    uint2* Ga  = (uint2*)(w);                                  // 4 MiB
    uint2* Gb  = (uint2*)(w + (size_t)NSITES * 16);            // 4 MiB
    H8*    Spa = (H8*)   (w + (size_t)NSITES * 32);            // 8 MiB
    H8*    Spb = (H8*)   (w + (size_t)NSITES * 64);            // 8 MiB

    prep_kernel<<<NSITES / 64, 256, 0, stream>>>(In, Weights, bias, Ga, Gb, Spa, Spb);
    gather_kernel<<<NSITES / 128, 256, 0, stream>>>(Spa, Ga, NN, out, 0);
    gather_kernel<<<NSITES / 128, 256, 0, stream>>>(Spb, Gb, NN, out, 2);
}

// Round 6
// 138.567 us; speedup vs baseline: 1.0798x; 1.0798x over previous
//
#include <hip/hip_runtime.h>
#include <hip/hip_fp16.h>

#define NSITES 262144
#define NB 1024            // gather grid blocks
#define USTRIDE 65536      // NB*64 sites per pipeline step

struct alignas(16) H8 { __half2 h[4]; };   // 8 fp16 values = 16 B
typedef __attribute__((ext_vector_type(2))) float floatx2;
typedef __attribute__((ext_vector_type(2))) unsigned int uintx2;
typedef __attribute__((ext_vector_type(4))) unsigned int uintx4;

// ws layout (round-4, known good):
//   G8 [NSITES][4] uint2 fp8, 32 B/site  (8 MiB)
//   Sp [NSITES][4] H8   fp16, 64 B/site  (16 MiB)

__global__ __launch_bounds__(256) void prep_kernel(
    const float* __restrict__ In,       // [4][8][NSITES]
    const float* __restrict__ Weights,  // [8][8][16]
    const float* __restrict__ bias,     // [8][8]
    uint2* __restrict__ G8,
    H8*    __restrict__ Sp)
{
    __shared__ float ws[8][8], wn[8][8], be[8];
    int t = threadIdx.x;
    if (t < 64) {
        int o = t >> 3, k = t & 7;
        float s0 = 0.f, s1 = 0.f;
        #pragma unroll
        for (int s = 0; s < 8; ++s) {
            s0 += Weights[s*128 + o*16 + k];
            s1 += Weights[s*128 + o*16 + 8 + k];
        }
        ws[o][k] = s0; wn[o][k] = s1;
    } else if (t < 72) {
        int o = t - 64;
        float s = 0.f;
        #pragma unroll
        for (int q = 0; q < 8; ++q) s += bias[q*8 + o];
        be[o] = s;
    }
    __syncthreads();

    int b    = t & 3;
    int sl   = t >> 2;
    int site = blockIdx.x * 64 + sl;

    float x[8];
    #pragma unroll
    for (int i = 0; i < 8; ++i)
        x[i] = In[(b*8 + i) * NSITES + site];

    float g[8], s[8];
    #pragma unroll
    for (int o = 0; o < 8; ++o) {
        float a0 = 0.f, a1 = be[o];
        #pragma unroll
        for (int i = 0; i < 8; ++i) {
            a0 = fmaf(wn[o][i], x[i], a0);
            a1 = fmaf(ws[o][i], x[i], a1);
        }
        g[o] = a0; s[o] = a1;
    }

    unsigned int w0 = 0, w1 = 0;
    w0 = __builtin_amdgcn_cvt_pk_fp8_f32(g[0], g[1], w0, false);
    w0 = __builtin_amdgcn_cvt_pk_fp8_f32(g[2], g[3], w0, true);
    w1 = __builtin_amdgcn_cvt_pk_fp8_f32(g[4], g[5], w1, false);
    w1 = __builtin_amdgcn_cvt_pk_fp8_f32(g[6], g[7], w1, true);
    G8[site*4 + b] = make_uint2(w0, w1);

    H8 sv;
    #pragma unroll
    for (int p = 0; p < 4; ++p) sv.h[p] = __floats2half2_rn(s[2*p], s[2*p+1]);
    Sp[site*4 + b] = sv;
}

// Rounds 0-4 all share {load-all -> wait-all -> compute-all, 1 site/thread}
// and all land at 47-48us with VALUBusy 43% — convoying, not a proven wall.
// This version: 4 sites per thread, software-pipelined. Site u+1's NN and
// gathers are issued BEFORE computing site u -> each wave self-hides ~1900cy
// of latency per unit. ALL VMEM ops are volatile asm (NN/Sp/G loads, out
// stores) so program order is pinned and counted vmcnt waits are exact
// (stores count in vmcnt on gfx9 -> they are the "8" allowance).
// Steady-state queue at each wait: [G_u(12) SP_u(1) NN_{u+1}(12) | S_{u-1}(8)]
// -> s_waitcnt vmcnt(8) retires exactly the loads needed, leaves stores.
__global__ __launch_bounds__(256) void gather_kernel(
    const H8*    __restrict__ Sp,
    const uint2* __restrict__ G8,
    const int*   __restrict__ NN,    // [13][NSITES], rows 1..12 used
    float*       __restrict__ out)   // [32][NSITES]
{
    int t  = threadIdx.x;          // 256
    int q  = t & 3;                // batch / record quad
    int sl = t >> 2;               // 0..63
    int n0 = blockIdx.x * 64 + sl; // unit-u site = n0 + u*USTRIDE

    int    m[2][12];
    uintx2 gw[2][12];
    uintx4 spw[2];

#define NN_ISSUE(BUF, U) do {                                                  \
    _Pragma("unroll")                                                          \
    for (int z_ = 0; z_ < 12; ++z_) {                                          \
        const int* p_ = NN + (z_ + 1) * NSITES + (n0 + (U) * USTRIDE);         \
        asm volatile("global_load_dword %0, %1, off nt"                        \
                     : "=v"(m[BUF][z_]) : "v"(p_));                            \
    } } while (0)

#define G_ISSUE(BUF) do {                                                      \
    _Pragma("unroll")                                                          \
    for (int z_ = 0; z_ < 12; ++z_) {                                          \
        const uint2* p_ = G8 + (m[BUF][z_] * 4 + q);                           \
        asm volatile("global_load_dwordx2 %0, %1, off"                         \
                     : "=v"(gw[BUF][z_]) : "v"(p_));                           \
    } } while (0)

#define SP_ISSUE(BUF, U) do {                                                  \
    const uintx4* p_ = (const uintx4*)Sp + ((n0 + (U) * USTRIDE) * 4 + q);     \
    asm volatile("global_load_dwordx4 %0, %1, off nt"                          \
                 : "=v"(spw[BUF]) : "v"(p_));                                  \
    } while (0)

#define COMPUTE_STORE(U, BUF) do {                                             \
    float sp_[8];                                                              \
    _Pragma("unroll")                                                          \
    for (int p_ = 0; p_ < 4; ++p_) {                                           \
        unsigned int wd_ = spw[BUF][p_];                                       \
        __half2 h_; __builtin_memcpy(&h_, &wd_, 4);                            \
        float2 f_ = __half22float2(h_);                                        \
        sp_[2*p_] = f_.x; sp_[2*p_+1] = f_.y;                                  \
    }                                                                          \
    float acc_[8], prod_[8];                                                   \
    _Pragma("unroll")                                                          \
    for (int k_ = 0; k_ < 8; ++k_) { acc_[k_] = 0.f; prod_[k_] = 1.f; }        \
    _Pragma("unroll")                                                          \
    for (int z_ = 0; z_ < 12; ++z_) {                                          \
        unsigned int gx_ = gw[BUF][z_][0];                                     \
        unsigned int gy_ = gw[BUF][z_][1];                                     \
        float g_[8]; floatx2 pp_;                                              \
        pp_ = __builtin_amdgcn_cvt_pk_f32_fp8(gx_, false); g_[0]=pp_[0]; g_[1]=pp_[1]; \
        pp_ = __builtin_amdgcn_cvt_pk_f32_fp8(gx_, true ); g_[2]=pp_[0]; g_[3]=pp_[1]; \
        pp_ = __builtin_amdgcn_cvt_pk_f32_fp8(gy_, false); g_[4]=pp_[0]; g_[5]=pp_[1]; \
        pp_ = __builtin_amdgcn_cvt_pk_f32_fp8(gy_, true ); g_[6]=pp_[0]; g_[7]=pp_[1]; \
        _Pragma("unroll")                                                      \
        for (int k_ = 0; k_ < 8; ++k_) {                                       \
            float x_  = sp_[k_] + g_[k_];                                      \
            float ax_ = fabsf(x_);                                             \
            acc_[k_] += fmaxf(x_, 0.f);                                        \
            float e_ = __builtin_amdgcn_exp2f(ax_ * -1.44269504f);             \
            prod_[k_] = fmaf(prod_[k_], e_, prod_[k_]);                        \
        }                                                                      \
    }                                                                          \
    int n_ = n0 + (U) * USTRIDE;                                               \
    _Pragma("unroll")                                                          \
    for (int k_ = 0; k_ < 8; ++k_) {                                           \
        float r_ = acc_[k_] + 0.69314718f * __builtin_amdgcn_logf(prod_[k_]);  \
        float* op_ = out + (q*8 + k_) * NSITES + n_;                           \
        asm volatile("global_store_dword %0, %1, off nt" :: "v"(op_), "v"(r_)); \
    } } while (0)

#define WAITV(N) do {                                                          \
    asm volatile("s_waitcnt vmcnt(" #N ")" ::: "memory");                      \
    __builtin_amdgcn_sched_barrier(0); } while (0)

    // ---- prologue: queue = NN0(12) NN1(12) ----
    NN_ISSUE(0, 0);
    NN_ISSUE(1, 1);
    WAITV(12);                 // NN0 done (NN1 in flight)
    G_ISSUE(0); SP_ISSUE(0, 0);   // queue: NN1(12) G0(12) SP0(1)

    // ---- iter 0 ----
    WAITV(0);                  // NN1 + G0 + SP0 done (one-time exposed latency)
    G_ISSUE(1); SP_ISSUE(1, 1);
    NN_ISSUE(0, 2);            // queue: G1 SP1 NN2
    COMPUTE_STORE(0, 0);       // + S0(8)

    // ---- iter 1 ----
    WAITV(8);                  // G1 SP1 NN2 done; S0 allowance
    G_ISSUE(0); SP_ISSUE(0, 2);
    NN_ISSUE(1, 3);            // queue: G2 SP2 NN3 (+S0 tail)
    COMPUTE_STORE(1, 1);       // + S1(8)

    // ---- iter 2 ----
    WAITV(8);                  // G2 SP2 NN3 done; S1 allowance
    G_ISSUE(1); SP_ISSUE(1, 3);   // queue: G3 SP3 (+S1 tail)
    COMPUTE_STORE(2, 0);       // + S2(8)

    // ---- iter 3 ----
    WAITV(8);                  // G3 SP3 done; S2 allowance
    COMPUTE_STORE(3, 1);

#undef NN_ISSUE
#undef G_ISSUE
#undef SP_ISSUE
#undef COMPUTE_STORE
#undef WAITV
}

extern "C" void kernel_launch(void* const* d_in, const int* in_sizes, int n_in,
                              void* d_out, int out_size, void* d_ws, size_t ws_size,
                              hipStream_t stream) {
    const float* In      = (const float*)d_in[0];
    const int*   NN      = (const int*)  d_in[1];
    const float* Weights = (const float*)d_in[2];
    const float* bias    = (const float*)d_in[3];
    float* out = (float*)d_out;

    uint2* G8 = (uint2*)d_ws;                             // 8 MiB
    H8*    Sp = (H8*)((char*)d_ws + (size_t)NSITES * 32); // 16 MiB

    prep_kernel<<<NSITES / 64, 256, 0, stream>>>(In, Weights, bias, G8, Sp);
    gather_kernel<<<NB, 256, 0, stream>>>(Sp, G8, NN, out);
}